// Round 3
// baseline (8428.737 us; speedup 1.0000x reference)
//
#include <hip/hip_runtime.h>
#include <hip/hip_bf16.h>

// Problem constants (Slot_Attention reference) — fp32 I/O per the reference.
#define B_    8
#define N_    1024
#define M_    4096
#define C_    512
#define KNN_  16
#define ITERS_ 3

static __device__ __forceinline__ double loadA(double x) { return x; }
static __device__ __forceinline__ float  loadA(float x)  { return x; }

// ---------------------------------------------------------------------------
// converters
// ---------------------------------------------------------------------------
__global__ void f32_to_f64_k(const float* __restrict__ in,
                             double* __restrict__ out, int n) {
    int i = blockIdx.x * blockDim.x + threadIdx.x;
    int stride = gridDim.x * blockDim.x;
    for (; i < n; i += stride) out[i] = (double)in[i];
}

__global__ void f64_to_f32_k(const double* __restrict__ in,
                             float* __restrict__ out, int n) {
    int i = blockIdx.x * blockDim.x + threadIdx.x;
    int stride = gridDim.x * blockDim.x;
    for (; i < n; i += stride) out[i] = (float)in[i];
}

// ---------------------------------------------------------------------------
// row inverse norms (fp64 to match numpy-f64 reference on the selection path)
// ---------------------------------------------------------------------------
__global__ void inv_norm_f64_k(const double* __restrict__ x, double* __restrict__ invn) {
    int row = blockIdx.x, lane = threadIdx.x;     // block = 64 (one wave)
    const double* p = x + (size_t)row * C_;
    double s = 0.0;
    for (int i = lane; i < C_; i += 64) { double v = p[i]; s += v * v; }
    for (int o = 32; o > 0; o >>= 1) s += __shfl_down(s, o);
    if (lane == 0) invn[row] = 1.0 / sqrt(s);
}

__global__ void inv_norm_f32_k(const float* __restrict__ x, double* __restrict__ invn) {
    int row = blockIdx.x, lane = threadIdx.x;
    const float* p = x + (size_t)row * C_;
    double s = 0.0;
    for (int i = lane; i < C_; i += 64) { double v = (double)p[i]; s += v * v; }
    for (int o = 32; o > 0; o >>= 1) s += __shfl_down(s, o);
    if (lane == 0) invn[row] = 1.0 / sqrt(s);
}

// ---------------------------------------------------------------------------
// corr[n][m] = (slots[n]/|slots[n]|) . (ref[m]/|ref[m]|), fp64, one batch
// 64x64 tile, 256 threads, 4x4 microtile
// ---------------------------------------------------------------------------
__global__ __launch_bounds__(256) void corr_k(const double* __restrict__ A,
                                              const float* __restrict__ Bm,
                                              const double* __restrict__ invA,
                                              const double* __restrict__ invB,
                                              double* __restrict__ corr) {
    __shared__ double As[16][68];
    __shared__ double Bs[16][68];
    const int tx = threadIdx.x, ty = threadIdx.y;
    const int t = ty * 16 + tx;
    const int lk = t & 15, lr = t >> 4;
    const int row0 = blockIdx.y * 64;   // n
    const int col0 = blockIdx.x * 64;   // m
    double acc[4][4] = {};
    for (int k0 = 0; k0 < C_; k0 += 16) {
#pragma unroll
        for (int p = 0; p < 4; ++p) {
            int r = lr + 16 * p;
            As[lk][r] = A[(size_t)(row0 + r) * C_ + k0 + lk] * invA[row0 + r];
            Bs[lk][r] = (double)Bm[(size_t)(col0 + r) * C_ + k0 + lk] * invB[col0 + r];
        }
        __syncthreads();
#pragma unroll
        for (int kk = 0; kk < 16; ++kk) {
            double a[4], b[4];
#pragma unroll
            for (int i = 0; i < 4; ++i) a[i] = As[kk][ty * 4 + i];
#pragma unroll
            for (int j = 0; j < 4; ++j) b[j] = Bs[kk][tx * 4 + j];
#pragma unroll
            for (int i = 0; i < 4; ++i)
#pragma unroll
                for (int j = 0; j < 4; ++j) acc[i][j] += a[i] * b[j];
        }
        __syncthreads();
    }
#pragma unroll
    for (int i = 0; i < 4; ++i) {
        size_t r = row0 + ty * 4 + i;
#pragma unroll
        for (int j = 0; j < 4; ++j)
            corr[r * M_ + col0 + tx * 4 + j] = acc[i][j];
    }
}

// ---------------------------------------------------------------------------
// top-16 (largest, tie -> smaller index) per row of corr (one batch)
// ---------------------------------------------------------------------------
__global__ __launch_bounds__(256) void topk_k(const double* __restrict__ corr,
                                              int* __restrict__ idx) {
    __shared__ double vals[M_];
    __shared__ double rv[256];
    __shared__ int ri[256];
    const int t = threadIdx.x;
    const int lrow = blockIdx.x;
    const double* rowp = corr + (size_t)lrow * M_;
    for (int i = t; i < M_; i += 256) vals[i] = rowp[i];
    __syncthreads();
    int* orow = idx + (size_t)lrow * KNN_;
    for (int r = 0; r < KNN_; ++r) {
        double bv = -1e300; int bi = M_;
        for (int i = t; i < M_; i += 256) {
            double v = vals[i];
            if (v > bv || (v == bv && i < bi)) { bv = v; bi = i; }
        }
        rv[t] = bv; ri[t] = bi;
        __syncthreads();
        for (int s = 128; s > 0; s >>= 1) {
            if (t < s) {
                double v2 = rv[t + s]; int i2 = ri[t + s];
                if (v2 > rv[t] || (v2 == rv[t] && i2 < ri[t])) { rv[t] = v2; ri[t] = i2; }
            }
            __syncthreads();
        }
        if (t == 0) { orow[r] = ri[0]; vals[ri[0]] = -1e300; }
        __syncthreads();
    }
}

// ---------------------------------------------------------------------------
// generic NN GEMM: out(rows x 512) = A(rows x 512) @ W(512 x 512) [+ res]
// W is fp32; CT = accumulator/output type; rows = gridDim.y*64
// ---------------------------------------------------------------------------
template <typename AT, typename CT, bool RES>
__global__ __launch_bounds__(256) void gemm_nn_k(const AT* __restrict__ A,
                                                 const float* __restrict__ W,
                                                 const CT* __restrict__ res,
                                                 CT* __restrict__ out) {
    __shared__ CT As[16][68];
    __shared__ CT Bs[16][68];
    const int tx = threadIdx.x, ty = threadIdx.y;
    const int t = ty * 16 + tx;
    const int lk = t & 15, lr = t >> 4;
    const int wc = t & 63, wk = t >> 6;
    const int row0 = blockIdx.y * 64, col0 = blockIdx.x * 64;
    CT acc[4][4] = {};
    for (int k0 = 0; k0 < C_; k0 += 16) {
#pragma unroll
        for (int p = 0; p < 4; ++p) {
            int r = lr + 16 * p;
            As[lk][r] = (CT)loadA(A[(size_t)(row0 + r) * C_ + k0 + lk]);
            Bs[wk + 4 * p][wc] = (CT)W[(size_t)(k0 + wk + 4 * p) * C_ + col0 + wc];
        }
        __syncthreads();
#pragma unroll
        for (int kk = 0; kk < 16; ++kk) {
            CT a[4], b[4];
#pragma unroll
            for (int i = 0; i < 4; ++i) a[i] = As[kk][ty * 4 + i];
#pragma unroll
            for (int j = 0; j < 4; ++j) b[j] = Bs[kk][tx * 4 + j];
#pragma unroll
            for (int i = 0; i < 4; ++i)
#pragma unroll
                for (int j = 0; j < 4; ++j) acc[i][j] += a[i] * b[j];
        }
        __syncthreads();
    }
#pragma unroll
    for (int i = 0; i < 4; ++i) {
        size_t r = row0 + ty * 4 + i;
#pragma unroll
        for (int j = 0; j < 4; ++j) {
            size_t o = r * C_ + col0 + tx * 4 + j;
            CT v = acc[i][j];
            if (RES) v += res[o];
            out[o] = v;
        }
    }
}

// ---------------------------------------------------------------------------
// per-row 16-way cross attention, one batch, IN-PLACE on q (q -> attn out).
// Safe: every thread's q reads happen before the reduction barriers; all
// writes happen after the final barrier.
// ---------------------------------------------------------------------------
__global__ __launch_bounds__(256) void attn_k(double* qo,               // aliased in/out
                                              const float* __restrict__ Kb,
                                              const float* __restrict__ Vb,
                                              const int* __restrict__ idx) {
    const int row = blockIdx.x;        // n within batch
    const int t = threadIdx.x;
    __shared__ int sidx[KNN_];
    __shared__ double red[KNN_][257];
    __shared__ double sw[KNN_];
    if (t < KNN_) sidx[t] = idx[(size_t)row * KNN_ + t];
    __syncthreads();
    double q0 = qo[(size_t)row * C_ + t];
    double q1 = qo[(size_t)row * C_ + t + 256];
    double p[KNN_];
#pragma unroll
    for (int j = 0; j < KNN_; ++j) {
        const float* kr = Kb + (size_t)sidx[j] * C_;
        p[j] = q0 * (double)kr[t] + q1 * (double)kr[t + 256];
    }
#pragma unroll
    for (int j = 0; j < KNN_; ++j) red[j][t] = p[j];
    __syncthreads();
    for (int s = 128; s > 0; s >>= 1) {
        if (t < s) {
#pragma unroll
            for (int j = 0; j < KNN_; ++j) red[j][t] += red[j][t + s];
        }
        __syncthreads();
    }
    if (t == 0) {
        const double scale = 1.0 / sqrt((double)C_);
        double mx = -1e300;
        for (int j = 0; j < KNN_; ++j) { double l = red[j][0] * scale; if (l > mx) mx = l; }
        double s = 0.0;
        for (int j = 0; j < KNN_; ++j) { double w = exp(red[j][0] * scale - mx); sw[j] = w; s += w; }
        double inv = 1.0 / s;
        for (int j = 0; j < KNN_; ++j) sw[j] *= inv;
    }
    __syncthreads();
    double o0 = 0.0, o1 = 0.0;
#pragma unroll
    for (int j = 0; j < KNN_; ++j) {
        const float* vr = Vb + (size_t)sidx[j] * C_;
        double w = sw[j];
        o0 += w * (double)vr[t];
        o1 += w * (double)vr[t + 256];
    }
    qo[(size_t)row * C_ + t] = o0;
    qo[(size_t)row * C_ + t + 256] = o1;
}

// ---------------------------------------------------------------------------
extern "C" void kernel_launch(void* const* d_in, const int* in_sizes, int n_in,
                              void* d_out, int out_size, void* d_ws, size_t ws_size,
                              hipStream_t stream) {
    const float* slots_in = (const float*)d_in[0];
    const float* reflist  = (const float*)d_in[1];
    const float* Wq = (const float*)d_in[2];
    const float* Wk = (const float*)d_in[3];
    const float* Wv = (const float*)d_in[4];
    const float* Wo = (const float*)d_in[5];
    // reference uses only the LAST ref in ref_pt_list
    const float* ref = reflist + ((size_t)in_sizes[1] - (size_t)B_ * M_ * C_);
    float* out = (float*)d_out;

    // workspace carve — per-batch layout, total ~52.2 MB
    char* w = (char*)d_ws;
    double* slots_b = (double*)w;  w += (size_t)N_ * C_ * 8;          //  4 MB
    double* corr    = (double*)w;  w += (size_t)N_ * M_ * 8;          // 32 MB
    float*  Kb      = (float*)w;   w += (size_t)M_ * C_ * 4;          //  8 MB
    float*  Vb      = (float*)w;   w += (size_t)M_ * C_ * 4;          //  8 MB
    double* inv_ns  = (double*)w;  w += (size_t)N_ * 8;               //  8 KB
    double* inv_nr  = (double*)w;  w += (size_t)M_ * 8;               // 32 KB
    int*    idxb    = (int*)w;     w += (size_t)N_ * KNN_ * 4;        // 64 KB
    double* qbuf    = corr;  // corr dead after topk; q/attn-out reuse it

    const int nslot_b = N_ * C_;   // 524288

    for (int b = 0; b < B_; ++b) {
        const float* slots_src = slots_in + (size_t)b * N_ * C_;
        const float* ref_b     = ref      + (size_t)b * M_ * C_;

        // per-batch one-time setup
        f32_to_f64_k<<<512, 256, 0, stream>>>(slots_src, slots_b, nslot_b);
        inv_norm_f32_k<<<M_, 64, 0, stream>>>(ref_b, inv_nr);
        gemm_nn_k<float, float, false>
            <<<dim3(C_ / 64, M_ / 64), dim3(16, 16), 0, stream>>>(ref_b, Wk, (const float*)nullptr, Kb);
        gemm_nn_k<float, float, false>
            <<<dim3(C_ / 64, M_ / 64), dim3(16, 16), 0, stream>>>(ref_b, Wv, (const float*)nullptr, Vb);

        for (int it = 0; it < ITERS_; ++it) {
            inv_norm_f64_k<<<N_, 64, 0, stream>>>(slots_b, inv_ns);
            corr_k<<<dim3(M_ / 64, N_ / 64), dim3(16, 16), 0, stream>>>(
                slots_b, ref_b, inv_ns, inv_nr, corr);
            topk_k<<<N_, 256, 0, stream>>>(corr, idxb);
            // q = slots @ Wq (into corr-aliased qbuf; corr fully consumed)
            gemm_nn_k<double, double, false>
                <<<dim3(C_ / 64, N_ / 64), dim3(16, 16), 0, stream>>>(slots_b, Wq, (const double*)nullptr, qbuf);
            attn_k<<<N_, 256, 0, stream>>>(qbuf, Kb, Vb, idxb);
            // slots += attnout @ Wo
            gemm_nn_k<double, double, true>
                <<<dim3(C_ / 64, N_ / 64), dim3(16, 16), 0, stream>>>(qbuf, Wo, slots_b, slots_b);
        }

        f64_to_f32_k<<<512, 256, 0, stream>>>(slots_b, out + (size_t)b * N_ * C_, nslot_b);
    }
}

// Round 5
// 5987.371 us; speedup vs baseline: 1.4078x; 1.4078x over previous
//
#include <hip/hip_runtime.h>
#include <hip/hip_bf16.h>

// Problem constants (Slot_Attention reference) — fp32 I/O per the reference.
#define B_    8
#define N_    1024
#define M_    4096
#define C_    512
#define KNN_  16
#define ITERS_ 3

typedef short short8 __attribute__((ext_vector_type(8)));   // 8 bf16 (4 VGPRs)
typedef float float4v __attribute__((ext_vector_type(4)));  // MFMA accum

static __device__ __forceinline__ double loadA(double x) { return x; }
static __device__ __forceinline__ float  loadA(float x)  { return x; }

// ---------------------------------------------------------------------------
// converters
// ---------------------------------------------------------------------------
__global__ void f32_to_f64_k(const float* __restrict__ in,
                             double* __restrict__ out, int n) {
    int i = blockIdx.x * blockDim.x + threadIdx.x;
    int stride = gridDim.x * blockDim.x;
    for (; i < n; i += stride) out[i] = (double)in[i];
}

__global__ void f64_to_f32_k(const double* __restrict__ in,
                             float* __restrict__ out, int n) {
    int i = blockIdx.x * blockDim.x + threadIdx.x;
    int stride = gridDim.x * blockDim.x;
    for (; i < n; i += stride) out[i] = (float)in[i];
}

// ---------------------------------------------------------------------------
// row inverse norms (fp64 on the selection path)
// ---------------------------------------------------------------------------
__global__ void inv_norm_f64_k(const double* __restrict__ x, double* __restrict__ invn) {
    int row = blockIdx.x, lane = threadIdx.x;     // block = 64 (one wave)
    const double* p = x + (size_t)row * C_;
    double s = 0.0;
    for (int i = lane; i < C_; i += 64) { double v = p[i]; s += v * v; }
    for (int o = 32; o > 0; o >>= 1) s += __shfl_down(s, o);
    if (lane == 0) invn[row] = 1.0 / sqrt(s);
}

__global__ void inv_norm_f32_k(const float* __restrict__ x, double* __restrict__ invn) {
    int row = blockIdx.x, lane = threadIdx.x;
    const float* p = x + (size_t)row * C_;
    double s = 0.0;
    for (int i = lane; i < C_; i += 64) { double v = (double)p[i]; s += v * v; }
    for (int o = 32; o > 0; o >>= 1) s += __shfl_down(s, o);
    if (lane == 0) invn[row] = 1.0 / sqrt(s);
}

// ---------------------------------------------------------------------------
// split kernels: normalized value -> bf16 hi + bf16 lo (hi+lo ~ fp32-accurate)
// ---------------------------------------------------------------------------
__global__ void split_slots_k(const double* __restrict__ s, const double* __restrict__ invn,
                              __hip_bfloat16* __restrict__ hi, __hip_bfloat16* __restrict__ lo,
                              int n) {
    int i = blockIdx.x * blockDim.x + threadIdx.x;
    int stride = gridDim.x * blockDim.x;
    for (; i < n; i += stride) {
        float x = (float)(s[i] * invn[i >> 9]);      // C_=512 per row
        __hip_bfloat16 h = __float2bfloat16(x);
        hi[i] = h;
        lo[i] = __float2bfloat16(x - __bfloat162float(h));
    }
}

__global__ void split_ref_k(const float* __restrict__ r, const double* __restrict__ invn,
                            __hip_bfloat16* __restrict__ hi, __hip_bfloat16* __restrict__ lo,
                            int n) {
    int i = blockIdx.x * blockDim.x + threadIdx.x;
    int stride = gridDim.x * blockDim.x;
    for (; i < n; i += stride) {
        float x = (float)((double)r[i] * invn[i >> 9]);
        __hip_bfloat16 h = __float2bfloat16(x);
        hi[i] = h;
        lo[i] = __float2bfloat16(x - __bfloat162float(h));
    }
}

// ---------------------------------------------------------------------------
// MFMA NT GEMM: C[I x J] fp32 = (Ah+Al)[I x 512] . (Bh+Bl)[J x 512]^T
// via 3 bf16 MFMAs per fragment pair (hi*hi + hi*lo + lo*hi).
// 128x128 tile / block (4 waves, 2x2), BK=32, grid = (J/128, I/128).
// Staging: thread t -> row t>>1, 16-elt half (t&1)*16, TWO uint4 loads
// (full 128x32 tile = 4096 bf16 = 256 thr x 16 elts).  [R4 bug: only half]
// ---------------------------------------------------------------------------
#define LDSS 40
__global__ __launch_bounds__(256) void mfma_nt_k(const __hip_bfloat16* __restrict__ Ahi,
                                                 const __hip_bfloat16* __restrict__ Alo,
                                                 const __hip_bfloat16* __restrict__ Bhi,
                                                 const __hip_bfloat16* __restrict__ Blo,
                                                 float* __restrict__ C, int J) {
    __shared__ short AhS[128 * LDSS];
    __shared__ short AlS[128 * LDSS];
    __shared__ short BhS[128 * LDSS];
    __shared__ short BlS[128 * LDSS];
    const int t = threadIdx.x;
    const int lane = t & 63, wid = t >> 6;
    const int quad = lane >> 4, l15 = lane & 15;
    const int wy = wid >> 1, wx = wid & 1;          // 2x2 wave grid
    const int row0 = blockIdx.y * 128;              // A rows (I)
    const int col0 = blockIdx.x * 128;              // B rows (J)
    const int tr = t >> 1, te = (t & 1) * 16;       // staging: row, elt offset

    float4v acc[4][4];
#pragma unroll
    for (int i = 0; i < 4; ++i)
#pragma unroll
        for (int j = 0; j < 4; ++j) acc[i][j] = (float4v){0.f, 0.f, 0.f, 0.f};

    const size_t aoff = (size_t)(row0 + tr) * C_ + te;
    const size_t boff = (size_t)(col0 + tr) * C_ + te;
    const int ldst = tr * LDSS + te;

    for (int k0 = 0; k0 < C_; k0 += 32) {
        __syncthreads();
        // stage 128x32 bf16 tiles of Ah/Al/Bh/Bl (32B per thread per array)
        *(uint4*)&AhS[ldst]     = *(const uint4*)(Ahi + aoff + k0);
        *(uint4*)&AhS[ldst + 8] = *(const uint4*)(Ahi + aoff + k0 + 8);
        *(uint4*)&AlS[ldst]     = *(const uint4*)(Alo + aoff + k0);
        *(uint4*)&AlS[ldst + 8] = *(const uint4*)(Alo + aoff + k0 + 8);
        *(uint4*)&BhS[ldst]     = *(const uint4*)(Bhi + boff + k0);
        *(uint4*)&BhS[ldst + 8] = *(const uint4*)(Bhi + boff + k0 + 8);
        *(uint4*)&BlS[ldst]     = *(const uint4*)(Blo + boff + k0);
        *(uint4*)&BlS[ldst + 8] = *(const uint4*)(Blo + boff + k0 + 8);
        __syncthreads();

        short8 ah[4], al[4], bh[4], bl[4];
#pragma unroll
        for (int rt = 0; rt < 4; ++rt) {
            int r = (wy * 64 + rt * 16 + l15) * LDSS + quad * 8;
            ah[rt] = *(const short8*)&AhS[r];
            al[rt] = *(const short8*)&AlS[r];
        }
#pragma unroll
        for (int ct = 0; ct < 4; ++ct) {
            int r = (wx * 64 + ct * 16 + l15) * LDSS + quad * 8;
            bh[ct] = *(const short8*)&BhS[r];
            bl[ct] = *(const short8*)&BlS[r];
        }
#pragma unroll
        for (int rt = 0; rt < 4; ++rt)
#pragma unroll
            for (int ct = 0; ct < 4; ++ct) {
                acc[rt][ct] = __builtin_amdgcn_mfma_f32_16x16x32_bf16(ah[rt], bh[ct], acc[rt][ct], 0, 0, 0);
                acc[rt][ct] = __builtin_amdgcn_mfma_f32_16x16x32_bf16(ah[rt], bl[ct], acc[rt][ct], 0, 0, 0);
                acc[rt][ct] = __builtin_amdgcn_mfma_f32_16x16x32_bf16(al[rt], bh[ct], acc[rt][ct], 0, 0, 0);
            }
    }

    // epilogue: D[m][n]: n = lane&15, m = quad*4 + reg
#pragma unroll
    for (int rt = 0; rt < 4; ++rt) {
        int mbase = row0 + wy * 64 + rt * 16 + quad * 4;
#pragma unroll
        for (int ct = 0; ct < 4; ++ct) {
            int n = col0 + wx * 64 + ct * 16 + l15;
#pragma unroll
            for (int reg = 0; reg < 4; ++reg)
                C[(size_t)(mbase + reg) * J + n] = acc[rt][ct][reg];
        }
    }
}

// ---------------------------------------------------------------------------
// fused candidate-select (fp32 corr, radix-histogram top>=32) + fp64 re-rank.
// Reproduces round-3's fp64 selection: term = (a*invA) * ((double)b*invB).
// One block per slot row.
// ---------------------------------------------------------------------------
__global__ __launch_bounds__(256) void select_rerank_k(const float* __restrict__ corr,
                                                       const double* __restrict__ slots,
                                                       const float* __restrict__ ref,
                                                       const double* __restrict__ inv_ns,
                                                       const double* __restrict__ inv_nr,
                                                       int* __restrict__ idx) {
    __shared__ unsigned hist[4096];
    __shared__ unsigned chunk[256];
    __shared__ double srow[C_];
    __shared__ int candIdx[256];
    __shared__ double candV[256];
    __shared__ double rv[256];
    __shared__ int rg[256];
    __shared__ int rp[256];
    __shared__ unsigned thrBin;
    __shared__ int cnt;

    const int row = blockIdx.x, t = threadIdx.x;
    const float* crow = corr + (size_t)row * M_;

    for (int i = t; i < 4096; i += 256) hist[i] = 0;
    {
        double ia = inv_ns[row];
        for (int i = t; i < C_; i += 256) srow[i] = slots[(size_t)row * C_ + i] * ia;
    }
    if (t == 0) cnt = 0;
    __syncthreads();

    // pass 1: histogram of order-preserving 12-bit prefix
#pragma unroll
    for (int j = 0; j < 16; ++j) {
        unsigned u = __float_as_uint(crow[t + 256 * j]);
        u = (u & 0x80000000u) ? ~u : (u | 0x80000000u);
        atomicAdd(&hist[u >> 20], 1u);
    }
    __syncthreads();

    // suffix sums: find largest bin T with count(bins >= T) >= 32
    {
        unsigned s = 0;
        for (int b = t * 16; b < t * 16 + 16; ++b) s += hist[b];
        chunk[t] = s;
    }
    __syncthreads();
    if (t == 0) {
        unsigned run = 0;
        for (int c = 255; c >= 0; --c) { unsigned tmp = chunk[c]; chunk[c] = run; run += tmp; }
    }
    __syncthreads();
    {
        unsigned prev = chunk[t];
        for (int b = t * 16 + 15; b >= t * 16; --b) {
            unsigned cur = prev + hist[b];
            if (cur >= 32u && prev < 32u) thrBin = (unsigned)b;
            prev = cur;
        }
    }
    __syncthreads();

    // pass 2: collect candidates
    const unsigned T = thrBin;
#pragma unroll
    for (int j = 0; j < 16; ++j) {
        int i = t + 256 * j;
        unsigned u = __float_as_uint(crow[i]);
        u = (u & 0x80000000u) ? ~u : (u | 0x80000000u);
        if ((u >> 20) >= T) {
            int p = atomicAdd(&cnt, 1);
            if (p < 256) candIdx[p] = i;
        }
    }
    __syncthreads();
    const int nc = cnt < 256 ? cnt : 256;

    // fp64 re-rank of candidates (wave per candidate, round-robin)
    {
        const int w = t >> 6, l = t & 63;
        for (int cj = w; cj < nc; cj += 4) {
            int col = candIdx[cj];
            const float* rp32 = ref + (size_t)col * C_;
            double ib = inv_nr[col];
            double s = 0.0;
            for (int k = l; k < C_; k += 64) s += srow[k] * ((double)rp32[k] * ib);
            for (int o = 32; o > 0; o >>= 1) s += __shfl_down(s, o);
            if (l == 0) candV[cj] = s;
        }
    }
    __syncthreads();

    // exact top-16 (value desc, global idx asc)
    int* orow = idx + (size_t)row * KNN_;
    for (int r = 0; r < KNN_; ++r) {
        double bv = -1e300; int bg = 0x7fffffff, bp = -1;
        for (int c = t; c < nc; c += 256) {
            double v = candV[c]; int g = candIdx[c];
            if (v > bv || (v == bv && g < bg)) { bv = v; bg = g; bp = c; }
        }
        rv[t] = bv; rg[t] = bg; rp[t] = bp;
        __syncthreads();
        for (int s = 128; s > 0; s >>= 1) {
            if (t < s) {
                if (rv[t + s] > rv[t] || (rv[t + s] == rv[t] && rg[t + s] < rg[t])) {
                    rv[t] = rv[t + s]; rg[t] = rg[t + s]; rp[t] = rp[t + s];
                }
            }
            __syncthreads();
        }
        if (t == 0) { orow[r] = rg[0]; candV[rp[0]] = -1e300; }
        __syncthreads();
    }
}

// ---------------------------------------------------------------------------
// generic NN GEMM: out(rows x 512) = A(rows x 512) @ W(512 x 512) [+ res]
// ---------------------------------------------------------------------------
template <typename AT, typename CT, bool RES>
__global__ __launch_bounds__(256) void gemm_nn_k(const AT* __restrict__ A,
                                                 const float* __restrict__ W,
                                                 const CT* __restrict__ res,
                                                 CT* __restrict__ out) {
    __shared__ CT As[16][68];
    __shared__ CT Bs[16][68];
    const int tx = threadIdx.x, ty = threadIdx.y;
    const int t = ty * 16 + tx;
    const int lk = t & 15, lr = t >> 4;
    const int wc = t & 63, wk = t >> 6;
    const int row0 = blockIdx.y * 64, col0 = blockIdx.x * 64;
    CT acc[4][4] = {};
    for (int k0 = 0; k0 < C_; k0 += 16) {
#pragma unroll
        for (int p = 0; p < 4; ++p) {
            int r = lr + 16 * p;
            As[lk][r] = (CT)loadA(A[(size_t)(row0 + r) * C_ + k0 + lk]);
            Bs[wk + 4 * p][wc] = (CT)W[(size_t)(k0 + wk + 4 * p) * C_ + col0 + wc];
        }
        __syncthreads();
#pragma unroll
        for (int kk = 0; kk < 16; ++kk) {
            CT a[4], b[4];
#pragma unroll
            for (int i = 0; i < 4; ++i) a[i] = As[kk][ty * 4 + i];
#pragma unroll
            for (int j = 0; j < 4; ++j) b[j] = Bs[kk][tx * 4 + j];
#pragma unroll
            for (int i = 0; i < 4; ++i)
#pragma unroll
                for (int j = 0; j < 4; ++j) acc[i][j] += a[i] * b[j];
        }
        __syncthreads();
    }
#pragma unroll
    for (int i = 0; i < 4; ++i) {
        size_t r = row0 + ty * 4 + i;
#pragma unroll
        for (int j = 0; j < 4; ++j) {
            size_t o = r * C_ + col0 + tx * 4 + j;
            CT v = acc[i][j];
            if (RES) v += res[o];
            out[o] = v;
        }
    }
}

// ---------------------------------------------------------------------------
// per-row 16-way cross attention, one batch, IN-PLACE on q (q -> attn out).
// ---------------------------------------------------------------------------
__global__ __launch_bounds__(256) void attn_k(double* qo,               // aliased in/out
                                              const float* __restrict__ Kb,
                                              const float* __restrict__ Vb,
                                              const int* __restrict__ idx) {
    const int row = blockIdx.x;        // n within batch
    const int t = threadIdx.x;
    __shared__ int sidx[KNN_];
    __shared__ double red[KNN_][257];
    __shared__ double sw[KNN_];
    if (t < KNN_) sidx[t] = idx[(size_t)row * KNN_ + t];
    __syncthreads();
    double q0 = qo[(size_t)row * C_ + t];
    double q1 = qo[(size_t)row * C_ + t + 256];
    double p[KNN_];
#pragma unroll
    for (int j = 0; j < KNN_; ++j) {
        const float* kr = Kb + (size_t)sidx[j] * C_;
        p[j] = q0 * (double)kr[t] + q1 * (double)kr[t + 256];
    }
#pragma unroll
    for (int j = 0; j < KNN_; ++j) red[j][t] = p[j];
    __syncthreads();
    for (int s = 128; s > 0; s >>= 1) {
        if (t < s) {
#pragma unroll
            for (int j = 0; j < KNN_; ++j) red[j][t] += red[j][t + s];
        }
        __syncthreads();
    }
    if (t == 0) {
        const double scale = 1.0 / sqrt((double)C_);
        double mx = -1e300;
        for (int j = 0; j < KNN_; ++j) { double l = red[j][0] * scale; if (l > mx) mx = l; }
        double s = 0.0;
        for (int j = 0; j < KNN_; ++j) { double w = exp(red[j][0] * scale - mx); sw[j] = w; s += w; }
        double inv = 1.0 / s;
        for (int j = 0; j < KNN_; ++j) sw[j] *= inv;
    }
    __syncthreads();
    double o0 = 0.0, o1 = 0.0;
#pragma unroll
    for (int j = 0; j < KNN_; ++j) {
        const float* vr = Vb + (size_t)sidx[j] * C_;
        double w = sw[j];
        o0 += w * (double)vr[t];
        o1 += w * (double)vr[t + 256];
    }
    qo[(size_t)row * C_ + t] = o0;
    qo[(size_t)row * C_ + t + 256] = o1;
}

// ---------------------------------------------------------------------------
extern "C" void kernel_launch(void* const* d_in, const int* in_sizes, int n_in,
                              void* d_out, int out_size, void* d_ws, size_t ws_size,
                              hipStream_t stream) {
    const float* slots_in = (const float*)d_in[0];
    const float* reflist  = (const float*)d_in[1];
    const float* Wq = (const float*)d_in[2];
    const float* Wk = (const float*)d_in[3];
    const float* Wv = (const float*)d_in[4];
    const float* Wo = (const float*)d_in[5];
    // reference uses only the LAST ref in ref_pt_list
    const float* ref = reflist + ((size_t)in_sizes[1] - (size_t)B_ * M_ * C_);
    float* out = (float*)d_out;

    // workspace carve — per-batch layout, ~48.3 MB (52.2 MB proven available)
    char* w = (char*)d_ws;
    double* slots_b = (double*)w;          w += (size_t)N_ * C_ * 8;      //  4 MB
    float*  corr    = (float*)w;           w += (size_t)N_ * M_ * 4;      // 16 MB
    float*  Kb      = (float*)w;           w += (size_t)M_ * C_ * 4;      //  8 MB
    float*  Vb      = (float*)w;           w += (size_t)M_ * C_ * 4;      //  8 MB
    double* inv_ns  = (double*)w;          w += (size_t)N_ * 8;
    double* inv_nr  = (double*)w;          w += (size_t)M_ * 8;
    __hip_bfloat16* Ahi = (__hip_bfloat16*)w; w += (size_t)N_ * C_ * 2;   //  1 MB
    __hip_bfloat16* Alo = (__hip_bfloat16*)w; w += (size_t)N_ * C_ * 2;   //  1 MB
    __hip_bfloat16* Bhi = (__hip_bfloat16*)w; w += (size_t)M_ * C_ * 2;   //  4 MB
    __hip_bfloat16* Blo = (__hip_bfloat16*)w; w += (size_t)M_ * C_ * 2;   //  4 MB
    int*    idxb    = (int*)w;             w += (size_t)N_ * KNN_ * 4;
    double* qbuf    = (double*)corr;  // corr dead after select; fp64 q fits in 16 MB

    const int nslot_b = N_ * C_;   // 524288

    for (int b = 0; b < B_; ++b) {
        const float* slots_src = slots_in + (size_t)b * N_ * C_;
        const float* ref_b     = ref      + (size_t)b * M_ * C_;

        // per-batch one-time setup
        f32_to_f64_k<<<512, 256, 0, stream>>>(slots_src, slots_b, nslot_b);
        inv_norm_f32_k<<<M_, 64, 0, stream>>>(ref_b, inv_nr);
        split_ref_k<<<2048, 256, 0, stream>>>(ref_b, inv_nr, Bhi, Blo, M_ * C_);
        gemm_nn_k<float, float, false>
            <<<dim3(C_ / 64, M_ / 64), dim3(16, 16), 0, stream>>>(ref_b, Wk, (const float*)nullptr, Kb);
        gemm_nn_k<float, float, false>
            <<<dim3(C_ / 64, M_ / 64), dim3(16, 16), 0, stream>>>(ref_b, Wv, (const float*)nullptr, Vb);

        for (int it = 0; it < ITERS_; ++it) {
            inv_norm_f64_k<<<N_, 64, 0, stream>>>(slots_b, inv_ns);
            split_slots_k<<<1024, 256, 0, stream>>>(slots_b, inv_ns, Ahi, Alo, N_ * C_);
            // corr (fp32, split-bf16 MFMA): 1024 x 4096
            mfma_nt_k<<<dim3(M_ / 128, N_ / 128), 256, 0, stream>>>(Ahi, Alo, Bhi, Blo, corr, M_);
            // candidate select + exact fp64 re-rank -> top-16 indices
            select_rerank_k<<<N_, 256, 0, stream>>>(corr, slots_b, ref_b, inv_ns, inv_nr, idxb);
            // q = slots @ Wq (fp64, into corr-aliased qbuf)
            gemm_nn_k<double, double, false>
                <<<dim3(C_ / 64, N_ / 64), dim3(16, 16), 0, stream>>>(slots_b, Wq, (const double*)nullptr, qbuf);
            attn_k<<<N_, 256, 0, stream>>>(qbuf, Kb, Vb, idxb);
            // slots += attnout @ Wo (fp64)
            gemm_nn_k<double, double, true>
                <<<dim3(C_ / 64, N_ / 64), dim3(16, 16), 0, stream>>>(qbuf, Wo, slots_b, slots_b);
        }

        f64_to_f32_k<<<512, 256, 0, stream>>>(slots_b, out + (size_t)b * N_ * C_, nslot_b);
    }
}

// Round 6
// 2757.803 us; speedup vs baseline: 3.0563x; 2.1711x over previous
//
#include <hip/hip_runtime.h>
#include <hip/hip_bf16.h>

// Problem constants (Slot_Attention reference) — fp32 I/O per the reference.
#define B_    8
#define N_    1024
#define M_    4096
#define C_    512
#define KNN_  16
#define ITERS_ 3

typedef short short8 __attribute__((ext_vector_type(8)));   // 8 bf16 (4 VGPRs)
typedef float float4v __attribute__((ext_vector_type(4)));  // MFMA accum

// ---------------------------------------------------------------------------
// converters
// ---------------------------------------------------------------------------
__global__ void f32_to_f64_k(const float* __restrict__ in,
                             double* __restrict__ out, int n) {
    int i = blockIdx.x * blockDim.x + threadIdx.x;
    int stride = gridDim.x * blockDim.x;
    for (; i < n; i += stride) out[i] = (double)in[i];
}

__global__ void f64_to_f32_k(const double* __restrict__ in,
                             float* __restrict__ out, int n) {
    int i = blockIdx.x * blockDim.x + threadIdx.x;
    int stride = gridDim.x * blockDim.x;
    for (; i < n; i += stride) out[i] = (float)in[i];
}

// ---------------------------------------------------------------------------
// fused fp64 row-norm + bf16 hi/lo split of the normalized row.
// One wave per row; sum order identical to rounds 3-5 (lane-stride 64,
// shfl_down reduce) -> inv-norms bit-exact.
// ---------------------------------------------------------------------------
__global__ void norm_split_ref_k(const float* __restrict__ ref,
                                 double* __restrict__ invn, double* __restrict__ rn,
                                 __hip_bfloat16* __restrict__ hi, __hip_bfloat16* __restrict__ lo) {
    const int row = blockIdx.x, lane = threadIdx.x;   // 64 threads
    const float* p = ref + (size_t)row * C_;
    double s = 0.0;
    for (int i = lane; i < C_; i += 64) { double v = (double)p[i]; s += v * v; }
    for (int o = 32; o > 0; o >>= 1) s += __shfl_down(s, o);
    s = __shfl(s, 0);
    if (lane == 0) { invn[row] = 1.0 / sqrt(s); rn[row] = sqrt(s); }
    const double inv = 1.0 / sqrt(s);
    for (int i = lane; i < C_; i += 64) {
        float x = (float)((double)p[i] * inv);
        __hip_bfloat16 h = __float2bfloat16(x);
        hi[(size_t)row * C_ + i] = h;
        lo[(size_t)row * C_ + i] = __float2bfloat16(x - __bfloat162float(h));
    }
}

__global__ void norm_split_slots_k(const double* __restrict__ slots,
                                   double* __restrict__ invn,
                                   __hip_bfloat16* __restrict__ hi, __hip_bfloat16* __restrict__ lo) {
    const int row = blockIdx.x, lane = threadIdx.x;   // 64 threads
    const double* p = slots + (size_t)row * C_;
    double s = 0.0;
    for (int i = lane; i < C_; i += 64) { double v = p[i]; s += v * v; }
    for (int o = 32; o > 0; o >>= 1) s += __shfl_down(s, o);
    s = __shfl(s, 0);
    if (lane == 0) invn[row] = 1.0 / sqrt(s);
    const double inv = 1.0 / sqrt(s);
    for (int i = lane; i < C_; i += 64) {
        float x = (float)(p[i] * inv);
        __hip_bfloat16 h = __float2bfloat16(x);
        hi[(size_t)row * C_ + i] = h;
        lo[(size_t)row * C_ + i] = __float2bfloat16(x - __bfloat162float(h));
    }
}

// ---------------------------------------------------------------------------
// transpose-split of Wk and Wv: Wt[c][k] = bf16split(W[k][c]); tiny.
// ---------------------------------------------------------------------------
__global__ void split_w_k(const float* __restrict__ Wk, const float* __restrict__ Wv,
                          __hip_bfloat16* __restrict__ kh, __hip_bfloat16* __restrict__ kl,
                          __hip_bfloat16* __restrict__ vh, __hip_bfloat16* __restrict__ vl) {
    int i = blockIdx.x * blockDim.x + threadIdx.x;
    int stride = gridDim.x * blockDim.x;
    for (; i < C_ * C_; i += stride) {
        int k = i >> 9, c = i & (C_ - 1);
        int o = c * C_ + k;
        float x = Wk[i];
        __hip_bfloat16 h = __float2bfloat16(x);
        kh[o] = h; kl[o] = __float2bfloat16(x - __bfloat162float(h));
        x = Wv[i];
        h = __float2bfloat16(x);
        vh[o] = h; vl[o] = __float2bfloat16(x - __bfloat162float(h));
    }
}

// ---------------------------------------------------------------------------
// split-bf16 MFMA NT GEMM: C[I x J] fp32 = (Ah+Al) . (Bh+Bl)^T (both row-major
// over K=512), 3 MFMAs per fragment pair. 128x128 tile, 4 waves (2x2), BK=32.
// z-batched via strides; optional per-A-row fp64 scale in the epilogue.
// ---------------------------------------------------------------------------
#define LDSS 40
__global__ __launch_bounds__(256) void mfma_nt_k(const __hip_bfloat16* __restrict__ Ahi,
                                                 const __hip_bfloat16* __restrict__ Alo,
                                                 size_t strideAz,
                                                 const __hip_bfloat16* __restrict__ Bhi,
                                                 const __hip_bfloat16* __restrict__ Blo,
                                                 size_t strideBz,
                                                 float* __restrict__ C, size_t strideCz,
                                                 int J,
                                                 const double* __restrict__ rowScale) {
    __shared__ short AhS[128 * LDSS];
    __shared__ short AlS[128 * LDSS];
    __shared__ short BhS[128 * LDSS];
    __shared__ short BlS[128 * LDSS];
    const int z = blockIdx.z;
    const __hip_bfloat16* Ah = Ahi + (size_t)z * strideAz;
    const __hip_bfloat16* Al = Alo + (size_t)z * strideAz;
    const __hip_bfloat16* Bh = Bhi + (size_t)z * strideBz;
    const __hip_bfloat16* Bl = Blo + (size_t)z * strideBz;
    float* Cz = C + (size_t)z * strideCz;

    const int t = threadIdx.x;
    const int lane = t & 63, wid = t >> 6;
    const int quad = lane >> 4, l15 = lane & 15;
    const int wy = wid >> 1, wx = wid & 1;          // 2x2 wave grid
    const int row0 = blockIdx.y * 128;              // A rows
    const int col0 = blockIdx.x * 128;              // B rows (C cols)
    const int tr = t >> 1, te = (t & 1) * 16;       // staging: row, elt offset

    float4v acc[4][4];
#pragma unroll
    for (int i = 0; i < 4; ++i)
#pragma unroll
        for (int j = 0; j < 4; ++j) acc[i][j] = (float4v){0.f, 0.f, 0.f, 0.f};

    const size_t aoff = (size_t)(row0 + tr) * C_ + te;
    const size_t boff = (size_t)(col0 + tr) * C_ + te;
    const int ldst = tr * LDSS + te;

    for (int k0 = 0; k0 < C_; k0 += 32) {
        __syncthreads();
        *(uint4*)&AhS[ldst]     = *(const uint4*)(Ah + aoff + k0);
        *(uint4*)&AhS[ldst + 8] = *(const uint4*)(Ah + aoff + k0 + 8);
        *(uint4*)&AlS[ldst]     = *(const uint4*)(Al + aoff + k0);
        *(uint4*)&AlS[ldst + 8] = *(const uint4*)(Al + aoff + k0 + 8);
        *(uint4*)&BhS[ldst]     = *(const uint4*)(Bh + boff + k0);
        *(uint4*)&BhS[ldst + 8] = *(const uint4*)(Bh + boff + k0 + 8);
        *(uint4*)&BlS[ldst]     = *(const uint4*)(Bl + boff + k0);
        *(uint4*)&BlS[ldst + 8] = *(const uint4*)(Bl + boff + k0 + 8);
        __syncthreads();

        short8 ah[4], al[4], bh[4], bl[4];
#pragma unroll
        for (int rt = 0; rt < 4; ++rt) {
            int r = (wy * 64 + rt * 16 + l15) * LDSS + quad * 8;
            ah[rt] = *(const short8*)&AhS[r];
            al[rt] = *(const short8*)&AlS[r];
        }
#pragma unroll
        for (int ct = 0; ct < 4; ++ct) {
            int r = (wx * 64 + ct * 16 + l15) * LDSS + quad * 8;
            bh[ct] = *(const short8*)&BhS[r];
            bl[ct] = *(const short8*)&BlS[r];
        }
#pragma unroll
        for (int rt = 0; rt < 4; ++rt)
#pragma unroll
            for (int ct = 0; ct < 4; ++ct) {
                acc[rt][ct] = __builtin_amdgcn_mfma_f32_16x16x32_bf16(ah[rt], bh[ct], acc[rt][ct], 0, 0, 0);
                acc[rt][ct] = __builtin_amdgcn_mfma_f32_16x16x32_bf16(ah[rt], bl[ct], acc[rt][ct], 0, 0, 0);
                acc[rt][ct] = __builtin_amdgcn_mfma_f32_16x16x32_bf16(al[rt], bh[ct], acc[rt][ct], 0, 0, 0);
            }
    }

    // epilogue: D[m][n]: n = lane&15, m = quad*4 + reg
#pragma unroll
    for (int rt = 0; rt < 4; ++rt) {
        int mbase = row0 + wy * 64 + rt * 16 + quad * 4;
#pragma unroll
        for (int ct = 0; ct < 4; ++ct) {
            int n = col0 + wx * 64 + ct * 16 + l15;
#pragma unroll
            for (int reg = 0; reg < 4; ++reg) {
                float v = acc[rt][ct][reg];
                if (rowScale) v *= (float)rowScale[mbase + reg];
                Cz[(size_t)(mbase + reg) * J + n] = v;
            }
        }
    }
}

// ---------------------------------------------------------------------------
// fused candidate-select (fp32 corr, radix top>=32) + exact fp64 re-rank.
// One block per global slot row (B*N blocks). Bit-identical per-row math
// to round 5.
// ---------------------------------------------------------------------------
__global__ __launch_bounds__(256) void select_rerank_k(const float* __restrict__ corr,
                                                       const double* __restrict__ slots,
                                                       const float* __restrict__ ref,
                                                       const double* __restrict__ inv_ns,
                                                       const double* __restrict__ inv_nr,
                                                       int* __restrict__ idx) {
    __shared__ unsigned hist[4096];
    __shared__ unsigned chunk[256];
    __shared__ double srow[C_];
    __shared__ int candIdx[256];
    __shared__ double candV[256];
    __shared__ double rv[256];
    __shared__ int rg[256];
    __shared__ int rp[256];
    __shared__ unsigned thrBin;
    __shared__ int cnt;

    const int row = blockIdx.x, t = threadIdx.x;
    const int bat = row >> 10;                       // N_=1024
    const float* crow = corr + (size_t)row * M_;
    const float* refb = ref + (size_t)bat * M_ * C_;
    const double* invB = inv_nr + (size_t)bat * M_;

    for (int i = t; i < 4096; i += 256) hist[i] = 0;
    {
        double ia = inv_ns[row];
        for (int i = t; i < C_; i += 256) srow[i] = slots[(size_t)row * C_ + i] * ia;
    }
    if (t == 0) cnt = 0;
    __syncthreads();

#pragma unroll
    for (int j = 0; j < 16; ++j) {
        unsigned u = __float_as_uint(crow[t + 256 * j]);
        u = (u & 0x80000000u) ? ~u : (u | 0x80000000u);
        atomicAdd(&hist[u >> 20], 1u);
    }
    __syncthreads();

    {
        unsigned s = 0;
        for (int b = t * 16; b < t * 16 + 16; ++b) s += hist[b];
        chunk[t] = s;
    }
    __syncthreads();
    if (t == 0) {
        unsigned run = 0;
        for (int c = 255; c >= 0; --c) { unsigned tmp = chunk[c]; chunk[c] = run; run += tmp; }
    }
    __syncthreads();
    {
        unsigned prev = chunk[t];
        for (int b = t * 16 + 15; b >= t * 16; --b) {
            unsigned cur = prev + hist[b];
            if (cur >= 32u && prev < 32u) thrBin = (unsigned)b;
            prev = cur;
        }
    }
    __syncthreads();

    const unsigned T = thrBin;
#pragma unroll
    for (int j = 0; j < 16; ++j) {
        int i = t + 256 * j;
        unsigned u = __float_as_uint(crow[i]);
        u = (u & 0x80000000u) ? ~u : (u | 0x80000000u);
        if ((u >> 20) >= T) {
            int p = atomicAdd(&cnt, 1);
            if (p < 256) candIdx[p] = i;
        }
    }
    __syncthreads();
    const int nc = cnt < 256 ? cnt : 256;

    {
        const int w = t >> 6, l = t & 63;
        for (int cj = w; cj < nc; cj += 4) {
            int col = candIdx[cj];
            const float* rp32 = refb + (size_t)col * C_;
            double ib = invB[col];
            double s = 0.0;
            for (int k = l; k < C_; k += 64) s += srow[k] * ((double)rp32[k] * ib);
            for (int o = 32; o > 0; o >>= 1) s += __shfl_down(s, o);
            if (l == 0) candV[cj] = s;
        }
    }
    __syncthreads();

    int* orow = idx + (size_t)row * KNN_;
    for (int r = 0; r < KNN_; ++r) {
        double bv = -1e300; int bg = 0x7fffffff, bp = -1;
        for (int c = t; c < nc; c += 256) {
            double v = candV[c]; int g = candIdx[c];
            if (v > bv || (v == bv && g < bg)) { bv = v; bg = g; bp = c; }
        }
        rv[t] = bv; rg[t] = bg; rp[t] = bp;
        __syncthreads();
        for (int s = 128; s > 0; s >>= 1) {
            if (t < s) {
                if (rv[t + s] > rv[t] || (rv[t + s] == rv[t] && rg[t + s] < rg[t])) {
                    rv[t] = rv[t + s]; rg[t] = rg[t + s]; rp[t] = rp[t + s];
                }
            }
            __syncthreads();
        }
        if (t == 0) { orow[r] = rg[0]; candV[rp[0]] = -1e300; }
        __syncthreads();
    }
}

// ---------------------------------------------------------------------------
// fp64 NN GEMM: out(rows x 512) = A(rows x 512) @ W(512x512 fp32) [+ res]
// 128x64 tile, 256 threads, 8x4 microtile, BK=16. Per-element k-order
// identical to rounds 3-5 -> bit-exact trajectory.
// ---------------------------------------------------------------------------
template <bool RES>
__global__ __launch_bounds__(256) void gemm_f64_k(const double* __restrict__ A,
                                                  const float* __restrict__ W,
                                                  const double* __restrict__ res,
                                                  double* __restrict__ out) {
    __shared__ double As[16][130];
    __shared__ double Bs[16][66];
    const int tx = threadIdx.x, ty = threadIdx.y;   // 16 x 16
    const int t = ty * 16 + tx;
    const int lk = t & 15, lr = t >> 4;
    const int wc = t & 63, wk = t >> 6;
    const int row0 = blockIdx.y * 128, col0 = blockIdx.x * 64;
    double acc[8][4] = {};
    for (int k0 = 0; k0 < C_; k0 += 16) {
#pragma unroll
        for (int p = 0; p < 8; ++p) {
            int r = lr + 16 * p;
            As[lk][r] = A[(size_t)(row0 + r) * C_ + k0 + lk];
        }
#pragma unroll
        for (int p = 0; p < 4; ++p)
            Bs[wk + 4 * p][wc] = (double)W[(size_t)(k0 + wk + 4 * p) * C_ + col0 + wc];
        __syncthreads();
#pragma unroll
        for (int kk = 0; kk < 16; ++kk) {
            double a[8], b[4];
#pragma unroll
            for (int i = 0; i < 8; ++i) a[i] = As[kk][ty * 8 + i];
#pragma unroll
            for (int j = 0; j < 4; ++j) b[j] = Bs[kk][tx * 4 + j];
#pragma unroll
            for (int i = 0; i < 8; ++i)
#pragma unroll
                for (int j = 0; j < 4; ++j) acc[i][j] += a[i] * b[j];
        }
        __syncthreads();
    }
#pragma unroll
    for (int i = 0; i < 8; ++i) {
        size_t r = row0 + ty * 8 + i;
#pragma unroll
        for (int j = 0; j < 4; ++j) {
            size_t o = r * C_ + col0 + tx * 4 + j;
            double v = acc[i][j];
            if (RES) v += res[o];
            out[o] = v;
        }
    }
}

// ---------------------------------------------------------------------------
// per-row 16-way cross attention, IN-PLACE on q, batched over B*N rows.
// ---------------------------------------------------------------------------
__global__ __launch_bounds__(256) void attn_k(double* qo,
                                              const float* __restrict__ Kb,
                                              const float* __restrict__ Vb,
                                              const int* __restrict__ idx) {
    const int row = blockIdx.x;        // b*N + n
    const int bat = row >> 10;
    const int t = threadIdx.x;
    __shared__ int sidx[KNN_];
    __shared__ double red[KNN_][257];
    __shared__ double sw[KNN_];
    if (t < KNN_) sidx[t] = idx[(size_t)row * KNN_ + t];
    __syncthreads();
    double q0 = qo[(size_t)row * C_ + t];
    double q1 = qo[(size_t)row * C_ + t + 256];
    double p[KNN_];
#pragma unroll
    for (int j = 0; j < KNN_; ++j) {
        const float* kr = Kb + ((size_t)bat * M_ + sidx[j]) * C_;
        p[j] = q0 * (double)kr[t] + q1 * (double)kr[t + 256];
    }
#pragma unroll
    for (int j = 0; j < KNN_; ++j) red[j][t] = p[j];
    __syncthreads();
    for (int s = 128; s > 0; s >>= 1) {
        if (t < s) {
#pragma unroll
            for (int j = 0; j < KNN_; ++j) red[j][t] += red[j][t + s];
        }
        __syncthreads();
    }
    if (t == 0) {
        const double scale = 1.0 / sqrt((double)C_);
        double mx = -1e300;
        for (int j = 0; j < KNN_; ++j) { double l = red[j][0] * scale; if (l > mx) mx = l; }
        double s = 0.0;
        for (int j = 0; j < KNN_; ++j) { double w = exp(red[j][0] * scale - mx); sw[j] = w; s += w; }
        double inv = 1.0 / s;
        for (int j = 0; j < KNN_; ++j) sw[j] *= inv;
    }
    __syncthreads();
    double o0 = 0.0, o1 = 0.0;
#pragma unroll
    for (int j = 0; j < KNN_; ++j) {
        const float* vr = Vb + ((size_t)bat * M_ + sidx[j]) * C_;
        double w = sw[j];
        o0 += w * (double)vr[t];
        o1 += w * (double)vr[t + 256];
    }
    qo[(size_t)row * C_ + t] = o0;
    qo[(size_t)row * C_ + t + 256] = o1;
}

// ---------------------------------------------------------------------------
extern "C" void kernel_launch(void* const* d_in, const int* in_sizes, int n_in,
                              void* d_out, int out_size, void* d_ws, size_t ws_size,
                              hipStream_t stream) {
    const float* slots_in = (const float*)d_in[0];
    const float* reflist  = (const float*)d_in[1];
    const float* Wq = (const float*)d_in[2];
    const float* Wk = (const float*)d_in[3];
    const float* Wv = (const float*)d_in[4];
    const float* Wo = (const float*)d_in[5];
    // reference uses only the LAST ref in ref_pt_list
    const float* ref = reflist + ((size_t)in_sizes[1] - (size_t)B_ * M_ * C_);
    float* out = (float*)d_out;

    const size_t NR = (size_t)B_ * N_;   // 8192 slot rows
    const size_t MR = (size_t)B_ * M_;   // 32768 ref rows

    // workspace carve — all-batch layout, ~389 MB of 512 MiB
    char* w = (char*)d_ws;
    double* slots_d = (double*)w;             w += NR * C_ * 8;            //  33.5 MB
    float*  corr    = (float*)w;              w += NR * M_ * 4;            // 134.2 MB
    float*  Kb      = (float*)w;              w += MR * C_ * 4;            //  67.1 MB
    float*  Vb      = (float*)w;              w += MR * C_ * 4;            //  67.1 MB
    __hip_bfloat16* Bhi = (__hip_bfloat16*)w; w += MR * C_ * 2;            //  33.5 MB
    __hip_bfloat16* Blo = (__hip_bfloat16*)w; w += MR * C_ * 2;            //  33.5 MB
    __hip_bfloat16* Ahi = (__hip_bfloat16*)w; w += NR * C_ * 2;            //   8.4 MB
    __hip_bfloat16* Alo = (__hip_bfloat16*)w; w += NR * C_ * 2;            //   8.4 MB
    __hip_bfloat16* Wkh = (__hip_bfloat16*)w; w += (size_t)C_ * C_ * 2;
    __hip_bfloat16* Wkl = (__hip_bfloat16*)w; w += (size_t)C_ * C_ * 2;
    __hip_bfloat16* Wvh = (__hip_bfloat16*)w; w += (size_t)C_ * C_ * 2;
    __hip_bfloat16* Wvl = (__hip_bfloat16*)w; w += (size_t)C_ * C_ * 2;
    double* inv_ns  = (double*)w;             w += NR * 8;
    double* inv_nr  = (double*)w;             w += MR * 8;
    double* rn      = (double*)w;             w += MR * 8;
    int*    idxb    = (int*)w;                w += NR * KNN_ * 4;
    double* qbuf    = (double*)corr;  // corr dead after select; fp64 q = 33.5 MB

    // ---- setup (once) ----
    f32_to_f64_k<<<4096, 256, 0, stream>>>(slots_in, slots_d, (int)(NR * C_));
    norm_split_ref_k<<<(int)MR, 64, 0, stream>>>(ref, inv_nr, rn, Bhi, Blo);
    split_w_k<<<512, 256, 0, stream>>>(Wk, Wv, Wkh, Wkl, Wvh, Wvl);
    // Kb = rn .* (ref_n @ Wk), Vb analogous — split-bf16 MFMA, rows = 32768
    mfma_nt_k<<<dim3(C_ / 128, MR / 128, 1), 256, 0, stream>>>(
        Bhi, Blo, 0, Wkh, Wkl, 0, Kb, 0, C_, rn);
    mfma_nt_k<<<dim3(C_ / 128, MR / 128, 1), 256, 0, stream>>>(
        Bhi, Blo, 0, Wvh, Wvl, 0, Vb, 0, C_, rn);

    for (int it = 0; it < ITERS_; ++it) {
        norm_split_slots_k<<<(int)NR, 64, 0, stream>>>(slots_d, inv_ns, Ahi, Alo);
        // corr (fp32, split-bf16 MFMA), z = batch
        mfma_nt_k<<<dim3(M_ / 128, N_ / 128, B_), 256, 0, stream>>>(
            Ahi, Alo, (size_t)N_ * C_, Bhi, Blo, (size_t)M_ * C_,
            corr, (size_t)N_ * M_, M_, nullptr);
        select_rerank_k<<<(int)NR, 256, 0, stream>>>(corr, slots_d, ref, inv_ns, inv_nr, idxb);
        // q = slots @ Wq (fp64, into corr-aliased qbuf)
        gemm_f64_k<false><<<dim3(C_ / 64, NR / 128), dim3(16, 16), 0, stream>>>(
            slots_d, Wq, (const double*)nullptr, qbuf);
        attn_k<<<(int)NR, 256, 0, stream>>>(qbuf, Kb, Vb, idxb);
        // slots += attnout @ Wo (fp64)
        gemm_f64_k<true><<<dim3(C_ / 64, NR / 128), dim3(16, 16), 0, stream>>>(
            qbuf, Wo, slots_d, slots_d);
    }

    f64_to_f32_k<<<4096, 256, 0, stream>>>(slots_d, out, (int)(NR * C_));
}